// Round 2
// baseline (660.308 us; speedup 1.0000x reference)
//
#include <hip/hip_runtime.h>
#include <hip/hip_bf16.h>
#include <stdint.h>

// GnnActor fused deepset actor. INPUTS/OUTPUTS ARE FLOAT32 (reference dtype).
// v3 (occupancy fix):
//  - 16-row batch tiles -> grid 1024 (4 blocks/CU co-resident, was 2).
//  - double-buffered As tile: prefetch store no longer drains at the GEMM1
//    barrier; loads for node n+1 issue after GEMM1(n), store to the other
//    buffer, consumed after the end-of-iteration barrier.
//  - B operands stream directly from L2-resident bf16 weights (no LDS, no
//    per-K-step barriers). 2 barriers per node.
//  - 5 transpose launches fused into 1 kernel.
//  - rho_heads on 16-row tiles (512 blocks, 2/CU).
// Scratch in module __device__ arrays (no d_ws use; graph-safe).

#define Bsz   8192
#define OBSW  1216      // 64 + 9*128
#define NH    256

typedef unsigned short u16;
typedef unsigned int   u32;

using bf16x8 = __attribute__((ext_vector_type(8))) short;
using f32x4  = __attribute__((ext_vector_type(4))) float;

// ---- module-scope scratch (~17.2 MB .bss) ----
__device__ u16   g_W1t[256 * 320];      // bf16(W1)^T  (N=256 rows, K=320)
__device__ u16   g_W2t[256 * 256];      // bf16(W2)^T
__device__ u16   g_Rt [256 * 256];      // bf16(Wrho)^T
__device__ u16   g_Wcat[64 * 256];      // [bf16(Wm)^T ; bf16(Ws)^T]
__device__ float g_pool2[2][Bsz * NH];  // per-nhalf pooled partials (f32)

__device__ __forceinline__ u16 f2bf(float f) {
  union { float f; u32 i; } v; v.f = f;
  u32 x = v.i;
  x += 0x7fffu + ((x >> 16) & 1u);   // RNE; values here are finite
  return (u16)(x >> 16);
}
__device__ __forceinline__ uint4 pack8(const float* f) {
  uint4 o;
  o.x = (u32)f2bf(f[0]) | ((u32)f2bf(f[1]) << 16);
  o.y = (u32)f2bf(f[2]) | ((u32)f2bf(f[3]) << 16);
  o.z = (u32)f2bf(f[4]) | ((u32)f2bf(f[5]) << 16);
  o.w = (u32)f2bf(f[6]) | ((u32)f2bf(f[7]) << 16);
  return o;
}
__device__ __forceinline__ void load8f(const float* p, float* f) {
  *(float4*)(f)     = *(const float4*)(p);
  *(float4*)(f + 4) = *(const float4*)(p + 4);
}

// ---------------- fused weight transpose+cast (one launch) ---------------------
// f32 in[K][N] -> bf16 out[N][K]; 224 blocks cover W1|W2|Wr|Wm|Ws.
__global__ __launch_bounds__(256)
void transpose_all(const float* __restrict__ W1, const float* __restrict__ W2,
                   const float* __restrict__ Wr, const float* __restrict__ Wm,
                   const float* __restrict__ Wsg) {
  __shared__ u16 tile[32][33];
  int bx = blockIdx.x;
  const float* in; u16* out; int K, N, row_off = 0, k0, n0;
  if (bx < 80)       { in = W1;  out = g_W1t;  K = 320; N = 256; k0 = (bx % 10) * 32; n0 = (bx / 10) * 32; }
  else if (bx < 144) { bx -= 80;  in = W2;  out = g_W2t;  K = 256; N = 256; k0 = (bx & 7) * 32; n0 = (bx >> 3) * 32; }
  else if (bx < 208) { bx -= 144; in = Wr;  out = g_Rt;   K = 256; N = 256; k0 = (bx & 7) * 32; n0 = (bx >> 3) * 32; }
  else if (bx < 216) { bx -= 208; in = Wm;  out = g_Wcat; K = 256; N = 32;  k0 = bx * 32; n0 = 0; }
  else               { bx -= 216; in = Wsg; out = g_Wcat; K = 256; N = 32;  k0 = bx * 32; n0 = 0; row_off = 32; }
  int c = threadIdx.x & 31, r0 = threadIdx.x >> 5;
  #pragma unroll
  for (int i = 0; i < 4; i++) {
    int r = r0 + i * 8;
    tile[r][c] = f2bf(in[(size_t)(k0 + r) * N + (n0 + c)]);
  }
  __syncthreads();
  #pragma unroll
  for (int i = 0; i < 4; i++) {
    int r = r0 + i * 8;
    out[(size_t)(n0 + r + row_off) * K + (k0 + c)] = tile[c][r];
  }
}

// gather node-n feature cols for one thread (8 obj cols + 8 segmax cols):
//  f[0] -> As cols 64+sck..71+sck   (object / iso node dims)
//  f[1] -> As cols 192+sck..199+sck (segmax over 8 edges / iso feats)
__device__ __forceinline__ void loadA16(
    int n, size_t rb, int sck,
    const float* __restrict__ obs, const float* __restrict__ ef,
    const float* __restrict__ iso, const float* __restrict__ isof,
    float f[2][8]) {
  if (n < 9) {
    load8f(obs + rb * OBSW + 64 + (size_t)n * 128 + sck, f[0]);
    const float* base = ef + (rb * 72 + n) * 128 + sck;   // edge e = n + 9j
    load8f(base, f[1]);
    #pragma unroll
    for (int j = 1; j < 8; j++) {
      float w[8];
      load8f(base + (size_t)j * 1152, w);
      #pragma unroll
      for (int q = 0; q < 8; q++) f[1][q] = fmaxf(f[1][q], w[q]);
    }
  } else {
    load8f(iso  + (rb * 3 + (n - 9)) * 128 + sck, f[0]);
    load8f(isof + (rb * 3 + (n - 9)) * 128 + sck, f[1]);
  }
}

// ---------------- fused node kernel --------------------------------------------
// grid = (Bsz/16) * 2; block (btile, nhalf) handles 16 rows x nodes nhalf*6..+6.
__global__ __launch_bounds__(256, 4)
void node_kernel(const float* __restrict__ obs, const float* __restrict__ ef,
                 const float* __restrict__ iso, const float* __restrict__ isof,
                 const float* __restrict__ b1, const float* __restrict__ b2) {
  // row strides: 328*2=656B (164 dw ≡ 4 mod 32), 264*2=528B (132 dw ≡ 4 mod 32)
  __shared__ __attribute__((aligned(16))) u16 As[2][16][328];  // dbuf 16x320
  __shared__ __attribute__((aligned(16))) u16 Ht[16][264];     // 16x256 hidden
  const int btile = blockIdx.x >> 1;
  const int nhalf = blockIdx.x & 1;
  const int b0 = btile * 16;
  const int tid = threadIdx.x;
  const int wave = tid >> 6, lane = tid & 63;
  const int nw = wave * 64, lrow = lane & 15, quad = lane >> 4;
  const int trow = tid >> 4, sck = (tid & 15) * 8;
  const size_t rb = (size_t)(b0 + trow);

  // prologue: body cols (0..63) into BOTH buffers; node n0 cols into buf 0
  {
    if (sck < 64) {
      float fb[8];
      load8f(obs + rb * OBSW + sck, fb);
      uint4 p = pack8(fb);
      *(uint4*)(&As[0][trow][sck]) = p;
      *(uint4*)(&As[1][trow][sck]) = p;
    }
    float f[2][8];
    loadA16(nhalf * 6, rb, sck, obs, ef, iso, isof, f);
    *(uint4*)(&As[0][trow][64  + sck]) = pack8(f[0]);
    *(uint4*)(&As[0][trow][192 + sck]) = pack8(f[1]);
  }
  __syncthreads();   // As[0](node n0) ready

  const f32x4 vzero = {0.f, 0.f, 0.f, 0.f};
  f32x4 pool[4];
  #pragma unroll
  for (int b = 0; b < 4; b++) pool[b] = vzero;

  int cur = 0;
  for (int nn = 0; nn < 6; nn++) {
    const int n = nhalf * 6 + nn;
    f32x4 acc[4];
    #pragma unroll
    for (int b = 0; b < 4; b++) acc[b] = vzero;

    // ---- GEMM1: K=320, A from As[cur], B direct from L2 — NO barriers ------
    #pragma unroll
    for (int kc = 0; kc < 10; kc++) {
      const int kk = kc * 32 + quad * 8;
      bf16x8 af = *(const bf16x8*)(&As[cur][lrow][kk]);
      #pragma unroll
      for (int nb = 0; nb < 4; nb++) {
        bf16x8 bq = *(const bf16x8*)(g_W1t + (size_t)(nw + nb * 16 + lrow) * 320 + kk);
        acc[nb] = __builtin_amdgcn_mfma_f32_16x16x32_bf16(af, bq, acc[nb], 0, 0, 0);
      }
    }

    // prefetch node n+1 into the OTHER buffer (no reader until end barrier)
    if (nn < 5) {
      float f[2][8];
      loadA16(n + 1, rb, sck, obs, ef, iso, isof, f);
      *(uint4*)(&As[cur ^ 1][trow][64  + sck]) = pack8(f[0]);
      *(uint4*)(&As[cur ^ 1][trow][192 + sck]) = pack8(f[1]);
    }

    // epilogue 1: Ht = bf16(relu(acc + b1))  (D: row=quad*4+i, col=lane&15)
    #pragma unroll
    for (int nb = 0; nb < 4; nb++) {
      int col = nw + nb * 16 + lrow;
      float bv = b1[col];
      #pragma unroll
      for (int i = 0; i < 4; i++)
        Ht[quad * 4 + i][col] = f2bf(fmaxf(acc[nb][i] + bv, 0.f));
    }
    __syncthreads();   // S1: Ht visible (As[cur] reads also done)

    #pragma unroll
    for (int b = 0; b < 4; b++) acc[b] = vzero;

    // ---- GEMM2: K=256, A from Ht, B direct from L2 — NO barriers -----------
    #pragma unroll
    for (int kc = 0; kc < 8; kc++) {
      const int kk = kc * 32 + quad * 8;
      bf16x8 af = *(const bf16x8*)(&Ht[lrow][kk]);
      #pragma unroll
      for (int nb = 0; nb < 4; nb++) {
        bf16x8 bq = *(const bf16x8*)(g_W2t + (size_t)(nw + nb * 16 + lrow) * 256 + kk);
        acc[nb] = __builtin_amdgcn_mfma_f32_16x16x32_bf16(af, bq, acc[nb], 0, 0, 0);
      }
    }
    // epilogue 2: pool += relu(acc + b2)
    #pragma unroll
    for (int nb = 0; nb < 4; nb++) {
      int col = nw + nb * 16 + lrow;
      float bv = b2[col];
      #pragma unroll
      for (int i = 0; i < 4; i++)
        pool[nb][i] += fmaxf(acc[nb][i] + bv, 0.f);
    }
    __syncthreads();   // S2: As[cur^1] writes visible; Ht reads done
    cur ^= 1;
  }

  // plain stores — each element written once by this block (no atomics)
  float* op = g_pool2[nhalf];
  #pragma unroll
  for (int nb = 0; nb < 4; nb++) {
    int col = nw + nb * 16 + lrow;
    #pragma unroll
    for (int i = 0; i < 4; i++) {
      int row = b0 + quad * 4 + i;
      op[(size_t)row * NH + col] = pool[nb][i];
    }
  }
}

// ---------------- rho + heads ---------------------------------------------------
// grid = Bsz/16. sum(g_pool2) -> GEMM3(relu,br) -> heads(N=64) -> clip -> out.
__global__ __launch_bounds__(256, 4)
void rho_heads(const float* __restrict__ br, const float* __restrict__ bm,
               const float* __restrict__ bs, float* __restrict__ out) {
  __shared__ __attribute__((aligned(16))) u16 As2[16][264];
  const int b0 = blockIdx.x * 16;
  const int tid = threadIdx.x;
  const int wave = tid >> 6, lane = tid & 63;
  const int nw = wave * 64, lrow = lane & 15, quad = lane >> 4;
  const int trow = tid >> 4, tcol = tid & 15;

  // stage pooled = half0 + half1 (f32) -> bf16 A-tile 16x256
  #pragma unroll
  for (int h = 0; h < 2; h++) {
    int col = tcol * 16 + h * 8;
    float f0[8], f1[8];
    load8f(g_pool2[0] + (size_t)(b0 + trow) * NH + col, f0);
    load8f(g_pool2[1] + (size_t)(b0 + trow) * NH + col, f1);
    #pragma unroll
    for (int q = 0; q < 8; q++) f0[q] += f1[q];
    *(uint4*)(&As2[trow][col]) = pack8(f0);
  }
  __syncthreads();

  const f32x4 vzero = {0.f, 0.f, 0.f, 0.f};
  f32x4 acc[4];
  #pragma unroll
  for (int b = 0; b < 4; b++) acc[b] = vzero;

  // GEMM3: K=256, B direct from g_Rt — no inner barriers
  #pragma unroll
  for (int kc = 0; kc < 8; kc++) {
    const int kk = kc * 32 + quad * 8;
    bf16x8 af = *(const bf16x8*)(&As2[lrow][kk]);
    #pragma unroll
    for (int nb = 0; nb < 4; nb++) {
      bf16x8 bq = *(const bf16x8*)(g_Rt + (size_t)(nw + nb * 16 + lrow) * 256 + kk);
      acc[nb] = __builtin_amdgcn_mfma_f32_16x16x32_bf16(af, bq, acc[nb], 0, 0, 0);
    }
  }
  __syncthreads();   // As2 reads done

  // r = bf16(relu(acc + br)) -> back into As2
  #pragma unroll
  for (int nb = 0; nb < 4; nb++) {
    int col = nw + nb * 16 + lrow;
    float bv = br[col];
    #pragma unroll
    for (int i = 0; i < 4; i++)
      As2[quad * 4 + i][col] = f2bf(fmaxf(acc[nb][i] + bv, 0.f));
  }
  __syncthreads();   // r visible

  // heads: N=64 (mean|log_std); wave w owns 16-col tile w. B direct from g_Wcat.
  f32x4 acc2 = vzero;
  #pragma unroll
  for (int kc = 0; kc < 8; kc++) {
    const int kk = kc * 32 + quad * 8;
    bf16x8 af = *(const bf16x8*)(&As2[lrow][kk]);
    bf16x8 bq = *(const bf16x8*)(g_Wcat + (size_t)(wave * 16 + lrow) * 256 + kk);
    acc2 = __builtin_amdgcn_mfma_f32_16x16x32_bf16(af, bq, acc2, 0, 0, 0);
  }

  int j = wave * 16 + lrow;
  #pragma unroll
  for (int i = 0; i < 4; i++) {
    int b = b0 + quad * 4 + i;
    if (j < 32) {
      out[(size_t)b * 32 + j] = acc2[i] + bm[j];
    } else {
      float v = acc2[i] + bs[j - 32];
      v = fminf(fmaxf(v, -20.f), 2.f);
      out[(size_t)Bsz * 32 + (size_t)b * 32 + (j - 32)] = v;
    }
  }
}

extern "C" void kernel_launch(void* const* d_in, const int* in_sizes, int n_in,
                              void* d_out, int out_size, void* d_ws, size_t ws_size,
                              hipStream_t stream) {
  const float* obs  = (const float*)d_in[0];
  const float* ef   = (const float*)d_in[1];
  // d_in[2] = edges_to (int32): tile(arange(9),8) -> edge e feeds node e%9
  const float* iso  = (const float*)d_in[3];
  const float* isof = (const float*)d_in[4];
  const float* W1   = (const float*)d_in[5];
  const float* b1   = (const float*)d_in[6];
  const float* W2   = (const float*)d_in[7];
  const float* b2   = (const float*)d_in[8];
  const float* Wr   = (const float*)d_in[9];
  const float* br   = (const float*)d_in[10];
  const float* Wm   = (const float*)d_in[11];
  const float* bm   = (const float*)d_in[12];
  const float* Wsg  = (const float*)d_in[13];
  const float* bs   = (const float*)d_in[14];
  float* out = (float*)d_out;
  (void)d_ws; (void)ws_size;

  transpose_all<<<224, 256, 0, stream>>>(W1, W2, Wr, Wm, Wsg);
  node_kernel<<<(Bsz / 16) * 2, 256, 0, stream>>>(obs, ef, iso, isof, b1, b2);
  rho_heads<<<Bsz / 16, 256, 0, stream>>>(br, bm, bs, out);
}